// Round 4
// baseline (147.539 us; speedup 1.0000x reference)
//
#include <hip/hip_runtime.h>
#include <cstddef>

#define NB 64
#define NL 4096
#define ND 512
#define NDP 64
#define LC 64
#define NLC (NL / LC)      // 64
#define NTASK (NB * NLC)   // 4096

// ---------------------------------------------------------------------------
// K1: partial queries. Block = (b, eq), 256 blocks x 128 threads.
// ---------------------------------------------------------------------------
__global__ void __launch_bounds__(128) queries_kernel(
    const float* __restrict__ source, const float* __restrict__ Wmi,
    const float* __restrict__ Wpi, float* __restrict__ qpm,
    float* __restrict__ qpp)
{
    __shared__ float s[128];
    const int b  = blockIdx.x >> 2;
    const int eq = blockIdx.x & 3;
    const int t  = threadIdx.x;
    const int e0 = eq * 128;
    s[t] = source[b * ND + e0 + t];
    __syncthreads();

    const int d0 = t * 4;
    float4 a0 = {0,0,0,0}, a1 = {0,0,0,0};
    #pragma unroll 4
    for (int e = 0; e < 128; e += 2) {
        const float4 w0 = *(const float4*)(Wmi + (size_t)(e0 + e) * ND + d0);
        const float4 w1 = *(const float4*)(Wmi + (size_t)(e0 + e + 1) * ND + d0);
        const float x0 = s[e], x1 = s[e + 1];
        a0.x = fmaf(x0, w0.x, a0.x); a0.y = fmaf(x0, w0.y, a0.y);
        a0.z = fmaf(x0, w0.z, a0.z); a0.w = fmaf(x0, w0.w, a0.w);
        a1.x = fmaf(x1, w1.x, a1.x); a1.y = fmaf(x1, w1.y, a1.y);
        a1.z = fmaf(x1, w1.z, a1.z); a1.w = fmaf(x1, w1.w, a1.w);
    }
    a0.x += a1.x; a0.y += a1.y; a0.z += a1.z; a0.w += a1.w;
    *(float4*)(qpm + (size_t)(b * 4 + eq) * ND + d0) = a0;

    if (t < NDP) {
        float c0 = 0.f, c1 = 0.f;
        #pragma unroll 4
        for (int e = 0; e < 128; e += 2) {
            c0 = fmaf(s[e],     Wpi[(size_t)(e0 + e) * NDP + t],     c0);
            c1 = fmaf(s[e + 1], Wpi[(size_t)(e0 + e + 1) * NDP + t], c1);
        }
        qpp[(b * 4 + eq) * NDP + t] = c0 + c1;
    }
}

// ---------------------------------------------------------------------------
// K2: fused scorer + online stats, DYNAMIC task scheduling.
// Persistent blocks pull (b,lc) tasks from an atomic counter (low lc first =
// LPT). Block = 4 waves; wave w handles rows l0+w, l0+w+4, ... with next-row
// prefetch; per-wave online (m,Z,S) + branch stats merged through LDS.
// Outputs identical regardless of which block runs which task.
// ---------------------------------------------------------------------------
__global__ void __launch_bounds__(256) pass1_kernel(
    const float* __restrict__ me, const float* __restrict__ pe,
    const float* __restrict__ qpm, const float* __restrict__ qpp,
    const int* __restrict__ mem_len,
    float* __restrict__ a_main, float* __restrict__ a_pos,
    float* __restrict__ Sbuf, float* __restrict__ MZ,
    float* __restrict__ MZa, float* __restrict__ MZp,
    int* __restrict__ counter)
{
    __shared__ float sS[4][ND];     // 8 KB: per-wave weighted row-sums
    __shared__ float sStat[4][6];   // per-wave {m,Z,Ma,Za,Mp,Zp}
    __shared__ int s_task;

    const int tid  = threadIdx.x;
    const int lane = tid & 63;
    const int wid  = tid >> 6;

    for (;;) {
        __syncthreads();   // protect s_task / sS reuse across iterations
        if (tid == 0) s_task = atomicAdd(counter, 1);
        __syncthreads();
        const int t = s_task;
        if (t >= NTASK) return;          // uniform exit

        const int lc  = t >> 6;          // ascending lc = longest tasks first
        const int b   = t & (NB - 1);
        const int len = mem_len[b];
        const int l0  = lc * LC;
        if (l0 >= len) continue;         // empty task (uniform)
        const int lend = min(l0 + LC, len);

        // per-wave q: sum of 4 e-segment partials (L2-resident)
        float4 q0 = {0,0,0,0}, q1 = {0,0,0,0};
        float qp = 0.f;
        #pragma unroll
        for (int eq = 0; eq < 4; ++eq) {
            const float4* qr = (const float4*)(qpm + (size_t)(b * 4 + eq) * ND);
            const float4 u0 = qr[lane], u1 = qr[64 + lane];
            q0.x += u0.x; q0.y += u0.y; q0.z += u0.z; q0.w += u0.w;
            q1.x += u1.x; q1.y += u1.y; q1.z += u1.z; q1.w += u1.w;
            qp += qpp[(b * 4 + eq) * NDP + lane];
        }

        float m = -1e30f, Z = 0.f;
        float Ma = -1e30f, Za = 0.f, Mp = -1e30f, Zp = 0.f;
        float4 S0 = {0,0,0,0}, S1 = {0,0,0,0};

        int l = l0 + wid;
        if (l < lend) {
            const float4* mr = (const float4*)(me + ((size_t)l * NB + b) * ND);
            float4 c0 = mr[lane];
            float4 c1 = mr[64 + lane];
            float  pv = pe[((size_t)l * NB + b) * NDP + lane];
            for (;;) {
                const int  ln   = min(l + 4, lend - 1);   // clamped prefetch
                const bool more = (l + 4) < lend;
                const float4* nr = (const float4*)(me + ((size_t)ln * NB + b) * ND);
                const float4 n0 = nr[lane];
                const float4 n1 = nr[64 + lane];
                const float  pn = pe[((size_t)ln * NB + b) * NDP + lane];

                float accm = c0.x*q0.x + c0.y*q0.y + c0.z*q0.z + c0.w*q0.w
                           + c1.x*q1.x + c1.y*q1.y + c1.z*q1.z + c1.w*q1.w;
                float accp = pv * qp;
                #pragma unroll
                for (int off = 32; off; off >>= 1) {
                    accm += __shfl_xor(accm, off);
                    accp += __shfl_xor(accp, off);
                }
                if (lane == 0) {
                    a_main[(size_t)b * NL + l] = accm;
                    a_pos [(size_t)b * NL + l] = accp;
                }

                // combined (av) online update
                const float sv = accm + accp;
                const float mn = fmaxf(m, sv);
                const float sc = __expf(m - mn);
                const float w  = __expf(sv - mn);
                Z = Z * sc + w;
                S0.x = fmaf(S0.x, sc, w * c0.x);  S0.y = fmaf(S0.y, sc, w * c0.y);
                S0.z = fmaf(S0.z, sc, w * c0.z);  S0.w = fmaf(S0.w, sc, w * c0.w);
                S1.x = fmaf(S1.x, sc, w * c1.x);  S1.y = fmaf(S1.y, sc, w * c1.y);
                S1.z = fmaf(S1.z, sc, w * c1.z);  S1.w = fmaf(S1.w, sc, w * c1.w);
                m = mn;

                // per-branch scalar online stats
                const float mna = fmaxf(Ma, accm);
                Za = Za * __expf(Ma - mna) + __expf(accm - mna);
                Ma = mna;
                const float mnp = fmaxf(Mp, accp);
                Zp = Zp * __expf(Mp - mnp) + __expf(accp - mnp);
                Mp = mnp;

                if (!more) break;
                c0 = n0; c1 = n1; pv = pn; l += 4;
            }
        }

        ((float4*)sS[wid])[lane]      = S0;
        ((float4*)sS[wid])[64 + lane] = S1;
        if (lane == 0) {
            sStat[wid][0] = m;  sStat[wid][1] = Z;
            sStat[wid][2] = Ma; sStat[wid][3] = Za;
            sStat[wid][4] = Mp; sStat[wid][5] = Zp;
        }
        __syncthreads();

        // merge the 4 per-wave states (associative flash combine)
        const float w0m = sStat[0][0], w1m = sStat[1][0],
                    w2m = sStat[2][0], w3m = sStat[3][0];
        const float mM = fmaxf(fmaxf(w0m, w1m), fmaxf(w2m, w3m));
        const float e0 = __expf(w0m - mM), e1 = __expf(w1m - mM),
                    e2 = __expf(w2m - mM), e3 = __expf(w3m - mM);
        const float2 v0 = ((const float2*)sS[0])[tid];
        const float2 v1 = ((const float2*)sS[1])[tid];
        const float2 v2 = ((const float2*)sS[2])[tid];
        const float2 v3 = ((const float2*)sS[3])[tid];
        float2 acc;
        acc.x = v0.x*e0 + v1.x*e1 + v2.x*e2 + v3.x*e3;
        acc.y = v0.y*e0 + v1.y*e1 + v2.y*e2 + v3.y*e3;
        ((float2*)(Sbuf + ((size_t)b * NLC + lc) * ND))[tid] = acc;

        if (tid == 0) {
            const int idx = b * NLC + lc;
            const float ZM = sStat[0][1]*e0 + sStat[1][1]*e1
                           + sStat[2][1]*e2 + sStat[3][1]*e3;
            MZ[2*idx] = mM;  MZ[2*idx+1] = ZM;

            const float A = fmaxf(fmaxf(sStat[0][2], sStat[1][2]),
                                  fmaxf(sStat[2][2], sStat[3][2]));
            const float ZA = sStat[0][3]*__expf(sStat[0][2]-A)
                           + sStat[1][3]*__expf(sStat[1][2]-A)
                           + sStat[2][3]*__expf(sStat[2][2]-A)
                           + sStat[3][3]*__expf(sStat[3][2]-A);
            MZa[2*idx] = A;  MZa[2*idx+1] = ZA;

            const float P = fmaxf(fmaxf(sStat[0][4], sStat[1][4]),
                                  fmaxf(sStat[2][4], sStat[3][4]));
            const float ZP = sStat[0][5]*__expf(sStat[0][4]-P)
                           + sStat[1][5]*__expf(sStat[1][4]-P)
                           + sStat[2][5]*__expf(sStat[2][4]-P)
                           + sStat[3][5]*__expf(sStat[3][4]-P);
            MZp[2*idx] = P;  MZp[2*idx+1] = ZP;
        }
    }
}

// ---------------------------------------------------------------------------
// K3: per-b stat combine. One wave per b (16 blocks x 4 waves). Pure shuffles.
// ---------------------------------------------------------------------------
__global__ void __launch_bounds__(256) combineA_kernel(
    const float* __restrict__ MZ, const float* __restrict__ MZa,
    const float* __restrict__ MZp, const int* __restrict__ mem_len,
    float* __restrict__ coef, float* __restrict__ stats)
{
    const int lane = threadIdx.x & 63;
    const int b = blockIdx.x * 4 + (threadIdx.x >> 6);
    const int nv = (mem_len[b] + LC - 1) >> 6;
    const bool v = lane < nv;
    const int idx = b * NLC + lane;
    const float m  = v ? MZ [2*idx] : -1e30f;
    const float z  = v ? MZ [2*idx+1] : 0.f;
    const float ma = v ? MZa[2*idx] : -1e30f;
    const float za = v ? MZa[2*idx+1] : 0.f;
    const float mp = v ? MZp[2*idx] : -1e30f;
    const float zp = v ? MZp[2*idx+1] : 0.f;

    float M = m, A = ma, P = mp;
    #pragma unroll
    for (int off = 32; off; off >>= 1) {
        M = fmaxf(M, __shfl_xor(M, off));
        A = fmaxf(A, __shfl_xor(A, off));
        P = fmaxf(P, __shfl_xor(P, off));
    }
    float ez = z * __expf(m - M);
    float ea = za * __expf(ma - A);
    float ep = zp * __expf(mp - P);
    #pragma unroll
    for (int off = 32; off; off >>= 1) {
        ez += __shfl_xor(ez, off);
        ea += __shfl_xor(ea, off);
        ep += __shfl_xor(ep, off);
    }
    const float invZ = 1.f / ez;
    coef[idx] = v ? __expf(m - M) * invZ : 0.f;
    if (lane == 0) {
        stats[b*8+0] = A;  stats[b*8+1] = 1.f / ea;
        stats[b*8+2] = P;  stats[b*8+3] = 1.f / ep;
        stats[b*8+4] = M;  stats[b*8+5] = invZ;
    }
}

// ---------------------------------------------------------------------------
// K4 (fused): blocks [0,512): c_t = sum_lc coef*S ; blocks [512,1536): finalize
// ---------------------------------------------------------------------------
__global__ void __launch_bounds__(256) combineBF_kernel(
    const float* __restrict__ Sbuf, const float* __restrict__ coef,
    const float* __restrict__ stats, const int* __restrict__ mem_len,
    float* __restrict__ c_t,
    float* __restrict__ a_main, float* __restrict__ a_pos,
    float* __restrict__ out_av)
{
    if (blockIdx.x < 512) {
        __shared__ float sh[4][64];
        const int b = blockIdx.x >> 3, dseg = blockIdx.x & 7;
        const int dl = threadIdx.x & 63, k = threadIdx.x >> 6;
        const int d = dseg * 64 + dl;
        const int nv = (mem_len[b] + LC - 1) >> 6;
        float acc = 0.f;
        for (int lc = k; lc < nv; lc += 4)
            acc = fmaf(coef[b * NLC + lc],
                       Sbuf[((size_t)b * NLC + lc) * ND + d], acc);
        sh[k][dl] = acc;
        __syncthreads();
        if (threadIdx.x < 64)
            c_t[b * ND + dseg * 64 + threadIdx.x] =
                sh[0][threadIdx.x] + sh[1][threadIdx.x] +
                sh[2][threadIdx.x] + sh[3][threadIdx.x];
    } else {
        const int idx = (blockIdx.x - 512) * 256 + threadIdx.x;
        const int b = idx >> 12;
        const int l = idx & (NL - 1);
        const float* st = stats + b * 8;
        const int len = mem_len[b];
        const float a = a_main[idx];
        const float p = a_pos[idx];
        const bool v = l < len;
        a_main[idx] = v ? __expf(a - st[0]) * st[1] : 0.f;
        a_pos [idx] = v ? __expf(p - st[2]) * st[3] : 0.f;
        out_av[idx] = v ? __expf(a + p - st[4]) * st[5] : 0.f;
    }
}

// ---------------------------------------------------------------------------
// K5: attn_h[b,e] = tanh(<[c_t, source], W_out[e,:]>)
// ---------------------------------------------------------------------------
__global__ void __launch_bounds__(256) out_kernel(
    const float* __restrict__ c_t, const float* __restrict__ source,
    const float* __restrict__ Wout, float* __restrict__ attn_h)
{
    __shared__ float cs[2 * ND];
    const int b = blockIdx.x >> 3;
    const int eg = blockIdx.x & 7;
    const int tid = threadIdx.x;

    for (int d = tid; d < ND; d += 256) {
        cs[d] = c_t[b * ND + d];
        cs[ND + d] = source[b * ND + d];
    }
    __syncthreads();

    const int wid = tid >> 6, lane = tid & 63;
    const float4* csv = (const float4*)cs;
    for (int e = eg * 64 + wid; e < eg * 64 + 64; e += 4) {
        const float4* wrow = (const float4*)(Wout + (size_t)e * 2 * ND);
        float acc = 0.f;
        #pragma unroll
        for (int j = 0; j < 4; ++j) {
            const float4 w = wrow[lane + 64 * j];
            const float4 c = csv[lane + 64 * j];
            acc += w.x * c.x + w.y * c.y + w.z * c.z + w.w * c.w;
        }
        #pragma unroll
        for (int off = 32; off; off >>= 1) acc += __shfl_xor(acc, off);
        if (lane == 0) attn_h[(size_t)b * ND + e] = tanhf(acc);
    }
}

// ---------------------------------------------------------------------------
extern "C" void kernel_launch(void* const* d_in, const int* in_sizes, int n_in,
                              void* d_out, int out_size, void* d_ws, size_t ws_size,
                              hipStream_t stream)
{
    const float* source = (const float*)d_in[0];
    const float* me     = (const float*)d_in[1];   // (L, B, D)
    const float* pe     = (const float*)d_in[2];   // (L, B, DP)
    const float* Wmi    = (const float*)d_in[3];   // (D, D)
    const float* Wpi    = (const float*)d_in[4];   // (D, DP)
    const float* Wout   = (const float*)d_in[5];   // (D, 2D)
    const int*   lens   = (const int*)d_in[6];     // (B,)

    float* out    = (float*)d_out;
    float* attn_h = out;                     // (B, D)
    float* av     = attn_h + NB * ND;        // (B, L)
    float* ma     = av + NB * NL;            // (B, L) raw a_main -> in-place
    float* pa     = ma + NB * NL;            // (B, L) raw a_pos  -> in-place

    float* ws    = (float*)d_ws;
    float* qpm   = ws;                              // NB*4*ND
    float* qpp   = qpm + NB * 4 * ND;               // NB*4*NDP
    float* Sbuf  = qpp + NB * 4 * NDP;              // NB*NLC*ND
    float* MZ    = Sbuf + (size_t)NB * NLC * ND;    // NB*NLC*2
    float* MZa   = MZ  + NB * NLC * 2;
    float* MZp   = MZa + NB * NLC * 2;
    float* coef  = MZp + NB * NLC * 2;              // NB*NLC
    float* c_t   = coef + NB * NLC;                 // NB*ND
    float* stats = c_t + NB * ND;                   // NB*8
    int*   ctr   = (int*)(stats + NB * 8);          // task counter

    hipMemsetAsync(ctr, 0, sizeof(int), stream);
    queries_kernel  <<<NB * 4, 128, 0, stream>>>(source, Wmi, Wpi, qpm, qpp);
    pass1_kernel    <<<1024, 256, 0, stream>>>(me, pe, qpm, qpp, lens,
                                               ma, pa, Sbuf, MZ, MZa, MZp, ctr);
    combineA_kernel <<<16, 256, 0, stream>>>(MZ, MZa, MZp, lens, coef, stats);
    combineBF_kernel<<<1536, 256, 0, stream>>>(Sbuf, coef, stats, lens,
                                               c_t, ma, pa, av);
    out_kernel      <<<NB * 8, 256, 0, stream>>>(c_t, source, Wout, attn_h);
}

// Round 5
// 111.323 us; speedup vs baseline: 1.3253x; 1.3253x over previous
//
#include <hip/hip_runtime.h>
#include <cstddef>

#define NB 64
#define NL 4096
#define ND 512
#define NDP 64
#define LC 64
#define NLC (NL / LC)   // 64

typedef float v2f __attribute__((ext_vector_type(2)));

__device__ __forceinline__ v2f fma2(v2f a, v2f b, v2f c) {
    return __builtin_elementwise_fma(a, b, c);
}

// ---------------------------------------------------------------------------
// K1: partial queries. Block = (b, eq), 256 blocks x 128 threads.
// ---------------------------------------------------------------------------
__global__ void __launch_bounds__(128) queries_kernel(
    const float* __restrict__ source, const float* __restrict__ Wmi,
    const float* __restrict__ Wpi, float* __restrict__ qpm,
    float* __restrict__ qpp)
{
    __shared__ float s[128];
    const int b  = blockIdx.x >> 2;
    const int eq = blockIdx.x & 3;
    const int t  = threadIdx.x;
    const int e0 = eq * 128;
    s[t] = source[b * ND + e0 + t];
    __syncthreads();

    const int d0 = t * 4;
    float4 a0 = {0,0,0,0}, a1 = {0,0,0,0};
    #pragma unroll 4
    for (int e = 0; e < 128; e += 2) {
        const float4 w0 = *(const float4*)(Wmi + (size_t)(e0 + e) * ND + d0);
        const float4 w1 = *(const float4*)(Wmi + (size_t)(e0 + e + 1) * ND + d0);
        const float x0 = s[e], x1 = s[e + 1];
        a0.x = fmaf(x0, w0.x, a0.x); a0.y = fmaf(x0, w0.y, a0.y);
        a0.z = fmaf(x0, w0.z, a0.z); a0.w = fmaf(x0, w0.w, a0.w);
        a1.x = fmaf(x1, w1.x, a1.x); a1.y = fmaf(x1, w1.y, a1.y);
        a1.z = fmaf(x1, w1.z, a1.z); a1.w = fmaf(x1, w1.w, a1.w);
    }
    a0.x += a1.x; a0.y += a1.y; a0.z += a1.z; a0.w += a1.w;
    *(float4*)(qpm + (size_t)(b * 4 + eq) * ND + d0) = a0;

    if (t < NDP) {
        float c0 = 0.f, c1 = 0.f;
        #pragma unroll 4
        for (int e = 0; e < 128; e += 2) {
            c0 = fmaf(s[e],     Wpi[(size_t)(e0 + e) * NDP + t],     c0);
            c1 = fmaf(s[e + 1], Wpi[(size_t)(e0 + e + 1) * NDP + t], c1);
        }
        qpp[(b * 4 + eq) * NDP + t] = c0 + c1;
    }
}

// ---------------------------------------------------------------------------
// K2: lean fused scorer. Static round-3 layout: wave = (b, lc-chunk of 64
// rows), independent waves, blockIdx ascending lc = LPT order.
// Per row: dot(pk) + single-value butterfly + uniform defer-rescale online
// update (1 exp/row typical). Branch softmax stats moved to K3.
// ---------------------------------------------------------------------------
__global__ void __launch_bounds__(256) pass1_kernel(
    const float* __restrict__ me, const float* __restrict__ pe,
    const float* __restrict__ qpm, const float* __restrict__ qpp,
    const int* __restrict__ mem_len,
    float* __restrict__ a_main, float* __restrict__ a_pos,
    float* __restrict__ Sbuf, float* __restrict__ MZ)
{
    __shared__ __align__(16) float qp_lds[4][NDP];
    const int lane = threadIdx.x & 63;
    const int wid  = threadIdx.x >> 6;
    const int bg   = blockIdx.x & 15;
    const int lc   = blockIdx.x >> 4;
    const int b    = (((bg + (lc >> 4)) & 15) << 2) | wid;

    const int len = mem_len[b];
    const int l0  = lc * LC;
    if (l0 >= len) return;
    const int nrow = min(LC, len - l0);

    // query fragments (lane-distributed) + qp into LDS
    float4 q0 = {0,0,0,0}, q1 = {0,0,0,0};
    float qp = 0.f;
    #pragma unroll
    for (int eq = 0; eq < 4; ++eq) {
        const float4* qr = (const float4*)(qpm + (size_t)(b * 4 + eq) * ND);
        const float4 u0 = qr[lane], u1 = qr[64 + lane];
        q0.x += u0.x; q0.y += u0.y; q0.z += u0.z; q0.w += u0.w;
        q1.x += u1.x; q1.y += u1.y; q1.z += u1.z; q1.w += u1.w;
        qp += qpp[(b * 4 + eq) * NDP + lane];
    }
    qp_lds[wid][lane] = qp;

    // pe: lane j computes the full 64-dot for row l0+j (scattered 16B loads,
    // qp broadcast from LDS). One coalesced a_pos store per chunk.
    float accp = 0.f;
    {
        const float4* pr = (const float4*)(pe + ((size_t)(l0 + lane) * NB + b) * NDP);
        #pragma unroll
        for (int k = 0; k < 16; ++k) {
            const float4 pv = pr[k];
            const float4 qv = *(const float4*)&qp_lds[wid][k * 4];
            accp = fmaf(pv.x, qv.x, accp);
            accp = fmaf(pv.y, qv.y, accp);
            accp = fmaf(pv.z, qv.z, accp);
            accp = fmaf(pv.w, qv.w, accp);
        }
        if (lane < nrow) a_pos[(size_t)b * NL + l0 + lane] = accp;
    }
    const int accp_i = __float_as_int(accp);

    // main row loop
    const size_t rstride = (size_t)NB * ND;
    const float* rp = me + ((size_t)l0 * NB + b) * ND;
    float4 c0 = ((const float4*)rp)[lane];
    float4 c1 = ((const float4*)rp)[64 + lane];

    float m = -1e30f, Z = 0.f, keep = 0.f;
    v2f S0 = {0,0}, S1 = {0,0}, S2 = {0,0}, S3 = {0,0};

    for (int i = 0; i < nrow; ++i) {
        const float* np = rp + ((i + 1 < nrow) ? rstride : 0);
        const float4 n0 = ((const float4*)np)[lane];
        const float4 n1 = ((const float4*)np)[64 + lane];

        v2f d2 = {0.f, 0.f};
        d2 = fma2((v2f){c0.x, c0.y}, (v2f){q0.x, q0.y}, d2);
        d2 = fma2((v2f){c0.z, c0.w}, (v2f){q0.z, q0.w}, d2);
        d2 = fma2((v2f){c1.x, c1.y}, (v2f){q1.x, q1.y}, d2);
        d2 = fma2((v2f){c1.z, c1.w}, (v2f){q1.z, q1.w}, d2);
        float accm = d2.x + d2.y;
        #pragma unroll
        for (int off = 32; off; off >>= 1)
            accm += __shfl_xor(accm, off);

        keep = (lane == i) ? accm : keep;
        const float ap = __int_as_float(__builtin_amdgcn_readlane(accp_i, i));
        const float sv = accm + ap;   // wave-uniform

        if (sv > m) {                 // uniform branch; w = exp(sv-sv) = 1
            const float sc = __expf(m - sv);
            const v2f sc2 = {sc, sc};
            Z = fmaf(Z, sc, 1.f);
            S0 = fma2(S0, sc2, (v2f){c0.x, c0.y});
            S1 = fma2(S1, sc2, (v2f){c0.z, c0.w});
            S2 = fma2(S2, sc2, (v2f){c1.x, c1.y});
            S3 = fma2(S3, sc2, (v2f){c1.z, c1.w});
            m = sv;
        } else {
            const float w = __expf(sv - m);
            const v2f w2 = {w, w};
            Z += w;
            S0 = fma2((v2f){c0.x, c0.y}, w2, S0);
            S1 = fma2((v2f){c0.z, c0.w}, w2, S1);
            S2 = fma2((v2f){c1.x, c1.y}, w2, S2);
            S3 = fma2((v2f){c1.z, c1.w}, w2, S3);
        }
        c0 = n0; c1 = n1;
        rp += rstride;
    }

    if (lane < nrow) a_main[(size_t)b * NL + l0 + lane] = keep;

    float* sp = Sbuf + ((size_t)b * NLC + lc) * ND;
    ((float4*)sp)[lane]      = (float4){S0.x, S0.y, S1.x, S1.y};
    ((float4*)sp)[64 + lane] = (float4){S2.x, S2.y, S3.x, S3.y};
    if (lane == 0) {
        MZ[2 * (b * NLC + lc)]     = m;
        MZ[2 * (b * NLC + lc) + 1] = Z;
    }
}

// ---------------------------------------------------------------------------
// K3: per-b stats + finalize, fused. Aligns read ONCE into registers; two
// block reductions (max, sumexp) for 3 streams; coef for c_t; in-place
// ma/pa/av writes.
// ---------------------------------------------------------------------------
__global__ void __launch_bounds__(1024) stats_finalize_kernel(
    const float* __restrict__ MZ, const int* __restrict__ mem_len,
    float* __restrict__ ma_io, float* __restrict__ pa_io,
    float* __restrict__ out_av, float* __restrict__ coef)
{
    __shared__ float red[16][6];
    __shared__ float bc[6];
    const int b = blockIdx.x;
    const int tid = threadIdx.x;
    const int lane = tid & 63, wid = tid >> 6;
    const int len = mem_len[b];

    float va[4], vp[4];
    float Am = -1e30f, Pm = -1e30f, Cm = -1e30f;
    #pragma unroll
    for (int k = 0; k < 4; ++k) {
        const int l = tid + k * 1024;
        va[k] = ma_io[(size_t)b * NL + l];
        vp[k] = pa_io[(size_t)b * NL + l];
        if (l < len) {
            Am = fmaxf(Am, va[k]);
            Pm = fmaxf(Pm, vp[k]);
            Cm = fmaxf(Cm, va[k] + vp[k]);
        }
    }
    #pragma unroll
    for (int off = 32; off; off >>= 1) {
        Am = fmaxf(Am, __shfl_xor(Am, off));
        Pm = fmaxf(Pm, __shfl_xor(Pm, off));
        Cm = fmaxf(Cm, __shfl_xor(Cm, off));
    }
    if (lane == 0) { red[wid][0] = Am; red[wid][1] = Pm; red[wid][2] = Cm; }
    __syncthreads();
    if (tid < 16) {
        float a = red[tid][0], p = red[tid][1], c = red[tid][2];
        #pragma unroll
        for (int off = 8; off; off >>= 1) {
            a = fmaxf(a, __shfl_xor(a, off));
            p = fmaxf(p, __shfl_xor(p, off));
            c = fmaxf(c, __shfl_xor(c, off));
        }
        if (tid == 0) { bc[0] = a; bc[1] = p; bc[2] = c; }
    }
    __syncthreads();
    const float MA = bc[0], MP = bc[1], MC = bc[2];

    float Az = 0.f, Pz = 0.f, Cz = 0.f;
    #pragma unroll
    for (int k = 0; k < 4; ++k) {
        const int l = tid + k * 1024;
        if (l < len) {
            Az += __expf(va[k] - MA);
            Pz += __expf(vp[k] - MP);
            Cz += __expf(va[k] + vp[k] - MC);
        }
    }
    #pragma unroll
    for (int off = 32; off; off >>= 1) {
        Az += __shfl_xor(Az, off);
        Pz += __shfl_xor(Pz, off);
        Cz += __shfl_xor(Cz, off);
    }
    if (lane == 0) { red[wid][3] = Az; red[wid][4] = Pz; red[wid][5] = Cz; }
    __syncthreads();
    if (tid < 16) {
        float a = red[tid][3], p = red[tid][4], c = red[tid][5];
        #pragma unroll
        for (int off = 8; off; off >>= 1) {
            a += __shfl_xor(a, off);
            p += __shfl_xor(p, off);
            c += __shfl_xor(c, off);
        }
        if (tid == 0) { bc[3] = a; bc[4] = p; bc[5] = c; }
    }
    __syncthreads();
    const float iA = 1.f / bc[3], iP = 1.f / bc[4], iC = 1.f / bc[5];

    if (tid < NLC) {
        const int nv = (len + LC - 1) >> 6;
        const float mlc = MZ[2 * (b * NLC + tid)];
        coef[b * NLC + tid] = (tid < nv) ? __expf(mlc - MC) * iC : 0.f;
    }

    #pragma unroll
    for (int k = 0; k < 4; ++k) {
        const int l = tid + k * 1024;
        const bool v = l < len;
        const size_t idx = (size_t)b * NL + l;
        ma_io[idx]  = v ? __expf(va[k] - MA) * iA : 0.f;
        pa_io[idx]  = v ? __expf(vp[k] - MP) * iP : 0.f;
        out_av[idx] = v ? __expf(va[k] + vp[k] - MC) * iC : 0.f;
    }
}

// ---------------------------------------------------------------------------
// K4: c_t[b,d] = sum_lc coef[b,lc] * Sbuf[b,lc,d]
// ---------------------------------------------------------------------------
__global__ void __launch_bounds__(256) ctx_kernel(
    const float* __restrict__ Sbuf, const float* __restrict__ coef,
    const int* __restrict__ mem_len, float* __restrict__ c_t)
{
    __shared__ float sh[3][64];
    const int b = blockIdx.x >> 3, dseg = blockIdx.x & 7;
    const int dl = threadIdx.x & 63, k = threadIdx.x >> 6;
    const int d = dseg * 64 + dl;
    const int nv = (mem_len[b] + LC - 1) >> 6;
    float acc = 0.f;
    for (int lcc = k; lcc < nv; lcc += 4)
        acc = fmaf(coef[b * NLC + lcc],
                   Sbuf[((size_t)b * NLC + lcc) * ND + d], acc);
    if (k) sh[k - 1][dl] = acc;
    __syncthreads();
    if (k == 0)
        c_t[b * ND + d] = acc + sh[0][dl] + sh[1][dl] + sh[2][dl];
}

// ---------------------------------------------------------------------------
// K5: attn_h[b,e] = tanh(<[c_t, source], W_out[e,:]>)
// ---------------------------------------------------------------------------
__global__ void __launch_bounds__(256) out_kernel(
    const float* __restrict__ c_t, const float* __restrict__ source,
    const float* __restrict__ Wout, float* __restrict__ attn_h)
{
    __shared__ float cs[2 * ND];
    const int b = blockIdx.x >> 3;
    const int eg = blockIdx.x & 7;
    const int tid = threadIdx.x;

    for (int d = tid; d < ND; d += 256) {
        cs[d] = c_t[b * ND + d];
        cs[ND + d] = source[b * ND + d];
    }
    __syncthreads();

    const int wid = tid >> 6, lane = tid & 63;
    const float4* csv = (const float4*)cs;
    for (int e = eg * 64 + wid; e < eg * 64 + 64; e += 4) {
        const float4* wrow = (const float4*)(Wout + (size_t)e * 2 * ND);
        float acc = 0.f;
        #pragma unroll
        for (int j = 0; j < 4; ++j) {
            const float4 w = wrow[lane + 64 * j];
            const float4 c = csv[lane + 64 * j];
            acc += w.x * c.x + w.y * c.y + w.z * c.z + w.w * c.w;
        }
        #pragma unroll
        for (int off = 32; off; off >>= 1) acc += __shfl_xor(acc, off);
        if (lane == 0) attn_h[(size_t)b * ND + e] = tanhf(acc);
    }
}

// ---------------------------------------------------------------------------
extern "C" void kernel_launch(void* const* d_in, const int* in_sizes, int n_in,
                              void* d_out, int out_size, void* d_ws, size_t ws_size,
                              hipStream_t stream)
{
    const float* source = (const float*)d_in[0];
    const float* me     = (const float*)d_in[1];   // (L, B, D)
    const float* pe     = (const float*)d_in[2];   // (L, B, DP)
    const float* Wmi    = (const float*)d_in[3];   // (D, D)
    const float* Wpi    = (const float*)d_in[4];   // (D, DP)
    const float* Wout   = (const float*)d_in[5];   // (D, 2D)
    const int*   lens   = (const int*)d_in[6];     // (B,)

    float* out    = (float*)d_out;
    float* attn_h = out;                     // (B, D)
    float* av     = attn_h + NB * ND;        // (B, L)
    float* ma     = av + NB * NL;            // (B, L) raw a_main -> in-place
    float* pa     = ma + NB * NL;            // (B, L) raw a_pos  -> in-place

    float* ws    = (float*)d_ws;
    float* qpm   = ws;                              // NB*4*ND
    float* qpp   = qpm + NB * 4 * ND;               // NB*4*NDP
    float* Sbuf  = qpp + NB * 4 * NDP;              // NB*NLC*ND
    float* MZ    = Sbuf + (size_t)NB * NLC * ND;    // NB*NLC*2
    float* coef  = MZ + NB * NLC * 2;               // NB*NLC
    float* c_t   = coef + NB * NLC;                 // NB*ND

    queries_kernel        <<<NB * 4, 128, 0, stream>>>(source, Wmi, Wpi, qpm, qpp);
    pass1_kernel          <<<NLC * 16, 256, 0, stream>>>(me, pe, qpm, qpp, lens,
                                                         ma, pa, Sbuf, MZ);
    stats_finalize_kernel <<<NB, 1024, 0, stream>>>(MZ, lens, ma, pa, av, coef);
    ctx_kernel            <<<NB * 8, 256, 0, stream>>>(Sbuf, coef, lens, c_t);
    out_kernel            <<<NB * 8, 256, 0, stream>>>(c_t, source, Wout, attn_h);
}